// Round 1
// baseline (439.609 us; speedup 1.0000x reference)
//
#include <hip/hip_runtime.h>
#include <math.h>

// Problem: IN=8192, HID=8192, OUT=1024, fp32.
// out = spiking_layer(spiking_layer(exp(x), W1), W2)
//
// R4 redesign: eliminate the idx-gather over W (uncoalesced, 64 lines/wave)
// and the duplicated W read. Per output row, ONE coalesced streaming pass:
//   pass A: W row -> registers, Wsum (bit-identical reduction to old K1)
//   pass B: against unsorted z (L1/L2-resident 32 KiB):
//           c  = #{j : z_j <= tmp}          (replaces binary search on zs)
//           Sw = sum_{z_j <= tmp} W[o,j]    (prefix sum via rank-threshold id:
//                                            {first k sorted} = {rank < k})
//           (bk,bw) = restricted key-argmax (the element at sorted pos c-1)
// Branches (faithful to reference scan semantics):
//   fc && c>=1            -> k=n-1 : Wc = Wsum - W[o, idx[n-1]]   (exact match
//                                    to old mode-2 single-element path)
//   fc && c==0            -> inf
//   !fc && c==n           -> inf
//   !fc && c==0           -> k=n-1 (as above)
//   !fc && c==1           -> inf
//   !fc && 2<=c<=n-1      -> k=c-1 : Wc = Sw - bw
//   Zc = csZ[k] from the unchanged scatter_scan (bit-identical csZ).
// Sort machinery (rank partials + single-block scatter_scan) kept: it is
// cheap and produces csZ/idx with the exact same bits as the passing R3.

static constexpr int NN     = 8192;   // columns of both W's
static constexpr int HID    = 8192;
static constexpr int OUTN   = 1024;
static constexpr int SEGS   = 8;
static constexpr int SEGLEN = NN / SEGS;     // 1024
static constexpr int RANKB  = 32 * SEGS;     // 256 rank blocks

// Total order on floats matching < (negatives, inf handled).
__device__ inline unsigned f2ord(float f) {
    unsigned u = __float_as_uint(f);
    return (u & 0x80000000u) ? ~u : (u | 0x80000000u);
}
__device__ inline unsigned long long sortkey(float f, int j) {
    return (((unsigned long long)f2ord(f)) << 13) | (unsigned)j;   // j < 8192
}

// Partial stable rank: block (jt,seg) counts, for each j in jt's 256-wide
// tile, how many keys in segment seg are < key(j). Plain store (no zeroing).
template <bool DOEXP>
__device__ inline void rank_block(const float* __restrict__ src,
                                  int* __restrict__ rank_part,
                                  unsigned long long* keys, int b) {
    int t = threadIdx.x;
    int jt = b >> 3, seg = b & 7;
    int j = jt * 256 + t;
    float zj = src[j];
    if (DOEXP) zj = expf(zj);
    unsigned long long K = sortkey(zj, j);
    int base = seg * SEGLEN;
    for (int i = t; i < SEGLEN; i += 256) {
        float zv = src[base + i];
        if (DOEXP) zv = expf(zv);
        keys[i] = sortkey(zv, base + i);
    }
    __syncthreads();
    int cnt = 0;
#pragma unroll 8
    for (int i = 0; i < SEGLEN; ++i) cnt += (keys[i] < K) ? 1 : 0;   // LDS broadcast
    rank_part[seg * NN + j] = cnt;
}

template <bool DOEXP>
__global__ void rank_kernel(const float* __restrict__ src,
                            int* __restrict__ rank_part) {
    __shared__ unsigned long long keys[SEGLEN];   // 8 KB
    rank_block<DOEXP>(src, rank_part, keys, blockIdx.x);
}

// Single block, 1024 threads. Sum the 8 partial ranks per j, scatter z
// (optionally exp'd) by rank, exclusive scan -> csZ[0..NN]; store idx and
// (layer 1 only) the unsorted z. csZ/idx bits identical to R3.
template <bool DOEXP>
__global__ void scatter_scan_kernel(const float* __restrict__ src,
                                    const int* __restrict__ rank_part,
                                    float* __restrict__ zun, int* __restrict__ idx,
                                    float* __restrict__ csZ) {
    __shared__ float zs_l[NN];                    // 32 KB
    __shared__ float wsum_s[16], woff_s[16];
    int t = threadIdx.x;
#pragma unroll
    for (int i = 0; i < 8; ++i) {
        int j = t + i * 1024;                     // coalesced
        int r = 0;
#pragma unroll
        for (int s = 0; s < SEGS; ++s) r += rank_part[s * NN + j];
        float z = src[j];
        if (DOEXP) { z = expf(z); zun[j] = z; }   // unsorted z for finalize
        zs_l[r] = z;                              // r is a permutation of [0,NN)
        idx[r] = j;
    }
    __syncthreads();
    int lane = t & 63, wv = t >> 6;               // 16 waves
    int base = t * 8;
    float v[8], s = 0.f;
#pragma unroll
    for (int i = 0; i < 8; ++i) { v[i] = zs_l[base + i]; s += v[i]; }
    float sc = s;                                 // inclusive wave scan of thread sums
    for (int off = 1; off < 64; off <<= 1) {
        float up = __shfl_up(sc, off);
        if (lane >= off) sc += up;
    }
    if (lane == 63) wsum_s[wv] = sc;
    __syncthreads();
    if (t == 0) {
        float acc = 0.f;
        for (int w = 0; w < 16; ++w) { woff_s[w] = acc; acc += wsum_s[w]; }
    }
    __syncthreads();
    float run = woff_s[wv] + (sc - s);            // exclusive base for this thread
#pragma unroll
    for (int i = 0; i < 8; ++i) { csZ[base + i] = run; run += v[i]; }
    if (t == 1023) csZ[NN] = run;                 // Zsum
}

// Fused rowsum + finalize: one block per output row, 256 threads.
// Streams the W row ONCE (coalesced float4 -> registers).
__global__ __launch_bounds__(256)
void finalize_fused_kernel(const float* __restrict__ W,
                           const float* __restrict__ zun,
                           const int* __restrict__ idx,
                           const float* __restrict__ csZ,
                           float* __restrict__ out) {
    int o = blockIdx.x;
    int t = threadIdx.x;
    int lane = t & 63, wv = t >> 6;
    const float4* row4 = (const float4*)(W + (size_t)o * NN);

    // Pass A: row -> registers, Wsum. EXACT reduction order of R3's K1:
    // per-thread strided float4 loop with (x+y)+(z+w), shfl_down 32..1,
    // 4-wave combine (r0+r1)+(r2+r3).
    __shared__ float red4[4];
    __shared__ float s_wsum, s_tmp;
    float4 w[8];
    float s = 0.f;
#pragma unroll
    for (int i = 0; i < 8; ++i) {
        float4 q = row4[t + i * 256];
        w[i] = q;
        s += (q.x + q.y) + (q.z + q.w);
    }
    for (int off = 32; off > 0; off >>= 1) s += __shfl_down(s, off);
    if (lane == 0) red4[wv] = s;
    __syncthreads();
    if (t == 0) {
        float Wsum = (red4[0] + red4[1]) + (red4[2] + red4[3]);
        float Zsum = csZ[NN];
        s_wsum = Wsum;
        s_tmp = Wsum * Zsum / (Wsum - 1.0f);
    }
    __syncthreads();
    float tmp = s_tmp;

    // Pass B: count / restricted sum / restricted key-argmax vs unsorted z.
    const float4* z4 = (const float4*)zun;
    int c = 0;
    float Sw = 0.f;
    unsigned long long bk = 0ull;
    float bw = 0.f;
#pragma unroll
    for (int i = 0; i < 8; ++i) {
        int q = t + i * 256;
        float4 zq = z4[q];
        float zz[4] = {zq.x, zq.y, zq.z, zq.w};
        float ww[4] = {w[i].x, w[i].y, w[i].z, w[i].w};
        int jb = q * 4;
#pragma unroll
        for (int l = 0; l < 4; ++l) {
            if (zz[l] <= tmp) {
                ++c;
                Sw += ww[l];
                unsigned long long K = sortkey(zz[l], jb + l);
                if (K > bk) { bk = K; bw = ww[l]; }
            }
        }
    }
    __shared__ int   sc_i[4];
    __shared__ float ssw[4], sbw[4];
    __shared__ unsigned long long sbk[4];
    for (int off = 32; off > 0; off >>= 1) {
        c  += __shfl_down(c, off);
        Sw += __shfl_down(Sw, off);
        unsigned long long ok = __shfl_down(bk, off);
        float ow = __shfl_down(bw, off);
        if (ok > bk) { bk = ok; bw = ow; }
    }
    if (lane == 0) { sc_i[wv] = c; ssw[wv] = Sw; sbk[wv] = bk; sbw[wv] = bw; }
    __syncthreads();

    if (t == 0) {
        int C = 0; float SwT = 0.f; unsigned long long bkT = 0ull; float bwT = 0.f;
        for (int v = 0; v < 4; ++v) {
            C += sc_i[v];
            SwT += ssw[v];
            if (sbk[v] > bkT) { bkT = sbk[v]; bwT = sbw[v]; }
        }
        float Wsum = s_wsum;
        bool fc = Wsum > 1.0f;
        int k = -1;
        bool empty = false;
        if (fc) {
            if (C >= 1) k = NN - 1;               // zs[0] <= tmp
            else empty = true;
        } else {
            if (C < NN) {                         // tmp < zs[n-1]
                if (C == 0) k = NN - 1;
                else if (C == 1) empty = true;    // k==0 -> empty
                else k = C - 1;
            } else empty = true;
        }
        if (empty) {
            out[o] = __builtin_inff();
        } else {
            float Wc;
            if (k == NN - 1) {
                // sum of all but the sorted-last element: exact match to R3's
                // mode-2 path (single-element backward gather).
                int jl = idx[NN - 1];
                float wl = W[(size_t)o * NN + jl];
                Wc = Wsum - wl;
            } else {
                // general path: Sw covers sorted ranks [0, C-1]; drop rank C-1.
                Wc = SwT - bwT;
            }
            float Zc = csZ[k];
            out[o] = Wc * Zc / (Wc - 1.0f);
        }
    }
}

extern "C" void kernel_launch(void* const* d_in, const int* in_sizes, int n_in,
                              void* d_out, int out_size, void* d_ws, size_t ws_size,
                              hipStream_t stream) {
    const float* x  = (const float*)d_in[0];
    const float* W1 = (const float*)d_in[1];   // [8192, 8192]
    const float* W2 = (const float*)d_in[2];   // [1024, 8192]
    float* out = (float*)d_out;                // [1024]

    char* ws = (char*)d_ws;
    size_t off = 0;
    auto alloc = [&](size_t bytes) -> void* {
        void* p = ws + off;
        off += (bytes + 255) & ~(size_t)255;
        return p;
    };
    float* zun1  = (float*)alloc((size_t)NN * 4);
    float* csZ1  = (float*)alloc((size_t)(NN + 1) * 4);
    float* z2    = (float*)alloc((size_t)NN * 4);
    float* csZ2  = (float*)alloc((size_t)(NN + 1) * 4);
    int* idx1    = (int*)alloc((size_t)NN * 4);
    int* idx2    = (int*)alloc((size_t)NN * 4);
    int* rank1_part = (int*)alloc((size_t)SEGS * NN * 4);   // plain stores, no zeroing
    int* rank2_part = (int*)alloc((size_t)SEGS * NN * 4);

    // Layer 1
    rank_kernel<true><<<RANKB, 256, 0, stream>>>(x, rank1_part);
    scatter_scan_kernel<true><<<1, 1024, 0, stream>>>(x, rank1_part, zun1, idx1, csZ1);
    finalize_fused_kernel<<<HID, 256, 0, stream>>>(W1, zun1, idx1, csZ1, z2);
    // Layer 2 (z2 is already the unsorted z array)
    rank_kernel<false><<<RANKB, 256, 0, stream>>>(z2, rank2_part);
    scatter_scan_kernel<false><<<1, 1024, 0, stream>>>(z2, rank2_part, nullptr, idx2, csZ2);
    finalize_fused_kernel<<<OUTN, 256, 0, stream>>>(W2, z2, idx2, csZ2, out);
}

// Round 2
// 409.723 us; speedup vs baseline: 1.0729x; 1.0729x over previous
//
#include <hip/hip_runtime.h>
#include <math.h>

// Problem: IN=8192, HID=8192, OUT=1024, fp32.
// out = spiking_layer(spiking_layer(exp(x), W1), W2)
//
// R5 restructure: shorten the serial kernel chain. Only csZ[k] (sorted-prefix
// sum) truly needs the sort; tmp feeds only comparisons with huge margins, so
// it can use an any-order Zsum; idx[NN-1] is just the sortkey-argmax.
// So per layer:
//   pre   : z=exp(x), any-order Zsum, key-argmax jmax  (layer2: folded into
//           scanCombine1), plus zeroing the atomic rank arrays.
//   fused : blocks [0,256) compute stable ranks (atomicAdd int -> exact),
//           blocks [256,..) stream the W rows ONCE: Wsum (exact R4 reduction
//           shape), wj = Wrow[jmax], and pass-B {C, Sw-bw} vs tmp'.
//   scanC : single block: scatter by rank -> blocked scan (EXACT R4
//           association, csZ kept in LDS) -> per-row branch logic -> outputs;
//           for layer 1 also computes layer-2 pre (Zsum2', jmax2) in-block.
// All float ops that reach `out` bits are unchanged from the R4 kernel that
// measured absmax 0.0: Wsum reduction, csZ scan association, Wc = Wsum - wj,
// final Wc*Zc/(Wc-1). Ranks/argmax/C are integer-exact.

static constexpr int NN     = 8192;   // columns of both W's
static constexpr int HID    = 8192;
static constexpr int OUTN   = 1024;
static constexpr int SEGS   = 8;
static constexpr int SEGLEN = NN / SEGS;     // 1024
static constexpr int RANKB  = 32 * SEGS;     // 256 rank blocks

// Total order on floats matching < (negatives, inf handled).
__device__ inline unsigned f2ord(float f) {
    unsigned u = __float_as_uint(f);
    return (u & 0x80000000u) ? ~u : (u | 0x80000000u);
}
__device__ inline unsigned long long sortkey(float f, int j) {
    return (((unsigned long long)f2ord(f)) << 13) | (unsigned)j;   // j < 8192
}

// K0: z1 = exp(x) -> zun; zero both rank arrays; Zsum' (any order; feeds only
// comparisons) ; jmax = stable argmax by sortkey (integer-exact).
__global__ void pre_kernel(const float* __restrict__ x,
                           float* __restrict__ zun,
                           int* __restrict__ rank1, int* __restrict__ rank2,
                           float* __restrict__ scal) {
    __shared__ float sred[16];
    __shared__ unsigned long long skey[16];
    int t = threadIdx.x;
#pragma unroll
    for (int i = 0; i < 8; ++i) { rank1[t + i * 1024] = 0; rank2[t + i * 1024] = 0; }
    float s = 0.f; unsigned long long bk = 0ull;
#pragma unroll
    for (int i = 0; i < 8; ++i) {
        int j = t + i * 1024;
        float z = expf(x[j]);
        zun[j] = z;
        s += z;
        unsigned long long K = sortkey(z, j);
        if (K > bk) bk = K;
    }
    int lane = t & 63, wv = t >> 6;
    for (int off = 32; off > 0; off >>= 1) {
        s += __shfl_down(s, off);
        unsigned long long ok = __shfl_down(bk, off);
        if (ok > bk) bk = ok;
    }
    if (lane == 0) { sred[wv] = s; skey[wv] = bk; }
    __syncthreads();
    if (t == 0) {
        float S = 0.f; unsigned long long B = 0ull;
        for (int w = 0; w < 16; ++w) { S += sred[w]; if (skey[w] > B) B = skey[w]; }
        scal[0] = S;
        ((int*)scal)[1] = (int)(B & 0x1FFFull);
    }
}

// Fused rank + W-stream. blocks [0,RANKB): partial stable ranks, accumulated
// with integer atomicAdd (deterministic). blocks [RANKB,..): one output row
// each; stream the row once (coalesced float4 -> regs), Wsum with the EXACT
// R4 reduction shape, then pass B {C, Sw, key-argmax-in-set} vs tmp'.
__global__ __launch_bounds__(256)
void fused_kernel(const float* __restrict__ W,
                  const float* __restrict__ zun,
                  int* __restrict__ rank,
                  const float* __restrict__ scal,
                  float4* __restrict__ stats) {
    __shared__ unsigned long long keys[SEGLEN];   // 8 KB (rank role)
    __shared__ float red4[4];
    __shared__ float s_wsum, s_tmp;
    __shared__ int   sc_i[4];
    __shared__ float ssw[4], sbw[4];
    __shared__ unsigned long long sbk[4];
    int b = blockIdx.x, t = threadIdx.x;
    if (b < RANKB) {
        int jt = b >> 3, seg = b & 7;
        int j = jt * 256 + t;
        unsigned long long K = sortkey(zun[j], j);
        int base = seg * SEGLEN;
        for (int i = t; i < SEGLEN; i += 256) keys[i] = sortkey(zun[base + i], base + i);
        __syncthreads();
        int cnt = 0;
#pragma unroll 8
        for (int i = 0; i < SEGLEN; ++i) cnt += (keys[i] < K) ? 1 : 0;   // LDS broadcast
        atomicAdd(&rank[j], cnt);
        return;
    }
    int o = b - RANKB;
    int lane = t & 63, wv = t >> 6;
    const float4* row4 = (const float4*)(W + (size_t)o * NN);

    // Pass A: row -> registers, Wsum (exact R4 reduction order).
    float4 w[8];
    float s = 0.f;
#pragma unroll
    for (int i = 0; i < 8; ++i) {
        float4 q = row4[t + i * 256];
        w[i] = q;
        s += (q.x + q.y) + (q.z + q.w);
    }
    for (int off = 32; off > 0; off >>= 1) s += __shfl_down(s, off);
    if (lane == 0) red4[wv] = s;
    __syncthreads();
    if (t == 0) {
        float Wsum = (red4[0] + red4[1]) + (red4[2] + red4[3]);
        s_wsum = Wsum;
        s_tmp = Wsum * scal[0] / (Wsum - 1.0f);   // tmp' : comparison-only
    }
    __syncthreads();
    float tmp = s_tmp;

    // Pass B: count / restricted sum / restricted key-argmax vs unsorted z.
    const float4* z4 = (const float4*)zun;
    int c = 0;
    float Sw = 0.f;
    unsigned long long bk = 0ull;
    float bw = 0.f;
#pragma unroll
    for (int i = 0; i < 8; ++i) {
        int q = t + i * 256;
        float4 zq = z4[q];
        float zz[4] = {zq.x, zq.y, zq.z, zq.w};
        float ww[4] = {w[i].x, w[i].y, w[i].z, w[i].w};
        int jb = q * 4;
#pragma unroll
        for (int l = 0; l < 4; ++l) {
            if (zz[l] <= tmp) {
                ++c;
                Sw += ww[l];
                unsigned long long K = sortkey(zz[l], jb + l);
                if (K > bk) { bk = K; bw = ww[l]; }
            }
        }
    }
    for (int off = 32; off > 0; off >>= 1) {
        c  += __shfl_down(c, off);
        Sw += __shfl_down(Sw, off);
        unsigned long long ok = __shfl_down(bk, off);
        float ow = __shfl_down(bw, off);
        if (ok > bk) { bk = ok; bw = ow; }
    }
    if (lane == 0) { sc_i[wv] = c; ssw[wv] = Sw; sbk[wv] = bk; sbw[wv] = bw; }
    __syncthreads();
    if (t == 0) {
        int C = 0; float SwT = 0.f; unsigned long long bkT = 0ull; float bwT = 0.f;
        for (int v = 0; v < 4; ++v) {
            C += sc_i[v];
            SwT += ssw[v];
            if (sbk[v] > bkT) { bkT = sbk[v]; bwT = sbw[v]; }
        }
        int jmax = ((const int*)scal)[1];
        float wj = W[(size_t)o * NN + jmax];      // exact: same load as R4's idx path
        float4 st;
        st.x = s_wsum;
        st.y = wj;
        st.z = SwT - bwT;                         // general-path Wc
        st.w = __int_as_float(C);
        stats[o] = st;
    }
}

// Single block, 1024 threads: scatter by rank, blocked scan (EXACT R4
// association) with csZ in LDS, per-row branch logic -> outputs. For MID
// (layer 1) also computes layer-2 pre stats (Zsum2', jmax2) in-block.
template <bool MID>
__global__ void scancombine_kernel(const float* __restrict__ zun,
                                   const int* __restrict__ rank,
                                   const float4* __restrict__ stats,
                                   int rows,
                                   float* __restrict__ outv,
                                   float* __restrict__ scal_out) {
    __shared__ float zs_l[NN];                    // 32 KB
    __shared__ float csZ_l[NN];                   // 32 KB
    __shared__ float wsum_s[16], woff_s[16];
    __shared__ unsigned long long skey2[16];
    int t = threadIdx.x;
#pragma unroll
    for (int i = 0; i < 8; ++i) {
        int j = t + i * 1024;                     // coalesced
        zs_l[rank[j]] = zun[j];                   // rank is a permutation of [0,NN)
    }
    __syncthreads();
    int lane = t & 63, wv = t >> 6;               // 16 waves
    int base = t * 8;
    float v[8], s = 0.f;
#pragma unroll
    for (int i = 0; i < 8; ++i) { v[i] = zs_l[base + i]; s += v[i]; }
    float sc = s;                                 // inclusive wave scan of thread sums
    for (int off = 1; off < 64; off <<= 1) {
        float up = __shfl_up(sc, off);
        if (lane >= off) sc += up;
    }
    if (lane == 63) wsum_s[wv] = sc;
    __syncthreads();
    if (t == 0) {
        float acc = 0.f;
        for (int w = 0; w < 16; ++w) { woff_s[w] = acc; acc += wsum_s[w]; }
    }
    __syncthreads();
    float run = woff_s[wv] + (sc - s);            // exclusive base for this thread
#pragma unroll
    for (int i = 0; i < 8; ++i) { csZ_l[base + i] = run; run += v[i]; }
    __syncthreads();

    // Combine: per-row branch logic (exact R4 decision tree + arithmetic).
    int rpt = rows >> 10;
    for (int i = 0; i < rpt; ++i) {
        int o = t + i * 1024;
        float4 st = stats[o];
        float Wsum = st.x, wj = st.y, SwB = st.z;
        int C = __float_as_int(st.w);
        bool fc = Wsum > 1.0f;
        int k = -1; bool empty = false;
        if (fc) {
            if (C >= 1) k = NN - 1; else empty = true;
        } else {
            if (C < NN) {
                if (C == 0) k = NN - 1;
                else if (C == 1) empty = true;
                else k = C - 1;
            } else empty = true;
        }
        float val;
        if (empty) val = __builtin_inff();
        else {
            float Wc = (k == NN - 1) ? (Wsum - wj) : SwB;
            val = Wc * csZ_l[k] / (Wc - 1.0f);
        }
        outv[o] = val;
        if (MID) zs_l[o] = val;                   // zs_l free after v[] extraction
    }
    if (MID) {
        __syncthreads();
        // Layer-2 pre: Zsum2' (any order) + jmax2 over z2 in LDS.
        float s2 = 0.f; unsigned long long bk = 0ull;
#pragma unroll
        for (int i = 0; i < 8; ++i) {
            int j = t + i * 1024;
            float z = zs_l[j];
            s2 += z;
            unsigned long long K = sortkey(z, j);
            if (K > bk) bk = K;
        }
        for (int off = 32; off > 0; off >>= 1) {
            s2 += __shfl_down(s2, off);
            unsigned long long ok = __shfl_down(bk, off);
            if (ok > bk) bk = ok;
        }
        if (lane == 0) { wsum_s[wv] = s2; skey2[wv] = bk; }
        __syncthreads();
        if (t == 0) {
            float S = 0.f; unsigned long long B = 0ull;
            for (int w = 0; w < 16; ++w) { S += wsum_s[w]; if (skey2[w] > B) B = skey2[w]; }
            scal_out[0] = S;
            ((int*)scal_out)[1] = (int)(B & 0x1FFFull);
        }
    }
}

extern "C" void kernel_launch(void* const* d_in, const int* in_sizes, int n_in,
                              void* d_out, int out_size, void* d_ws, size_t ws_size,
                              hipStream_t stream) {
    const float* x  = (const float*)d_in[0];
    const float* W1 = (const float*)d_in[1];   // [8192, 8192]
    const float* W2 = (const float*)d_in[2];   // [1024, 8192]
    float* out = (float*)d_out;                // [1024]

    char* ws = (char*)d_ws;
    size_t off = 0;
    auto alloc = [&](size_t bytes) -> void* {
        void* p = ws + off;
        off += (bytes + 255) & ~(size_t)255;
        return p;
    };
    float*  zun1   = (float*)alloc((size_t)NN * 4);
    float*  z2     = (float*)alloc((size_t)NN * 4);
    float4* stats1 = (float4*)alloc((size_t)HID * 16);
    float4* stats2 = (float4*)alloc((size_t)OUTN * 16);
    int*    rank1  = (int*)alloc((size_t)NN * 4);
    int*    rank2  = (int*)alloc((size_t)NN * 4);
    float*  scal1  = (float*)alloc(256);
    float*  scal2  = (float*)alloc(256);

    // K0: z1=exp(x), zero ranks, Zsum1', jmax1
    pre_kernel<<<1, 1024, 0, stream>>>(x, zun1, rank1, rank2, scal1);
    // K1: ranks(z1) || stream W1 -> per-row stats
    fused_kernel<<<RANKB + HID, 256, 0, stream>>>(W1, zun1, rank1, scal1, stats1);
    // K2: scan + combine -> z2 ; layer-2 pre (Zsum2', jmax2)
    scancombine_kernel<true><<<1, 1024, 0, stream>>>(zun1, rank1, stats1, HID, z2, scal2);
    // K3: ranks(z2) || stream W2 -> per-row stats
    fused_kernel<<<RANKB + OUTN, 256, 0, stream>>>(W2, z2, rank2, scal2, stats2);
    // K4: scan + combine -> out
    scancombine_kernel<false><<<1, 1024, 0, stream>>>(z2, rank2, stats2, OUTN, out, nullptr);
}